// Round 1
// baseline (118.460 us; speedup 1.0000x reference)
//
#include <hip/hip_runtime.h>

#define NSP    1024
#define ROWS   8     // batch rows per row-group (was 4): halves terms_T re-reads
#define BLK    256   // gather block: 256 threads, each owns 1 species of a quarter
#define QUARTS 4     // species quarters per row-group
#define MAXK   160   // max total terms per species column (Poisson λ≈78; max over 1024 ≈ 106)

// ---- workspace layout (bytes) ----
// counts  : int[NSP]              @ 0      (merged 1st+2nd order count per species)
// terms_T : int2[MAXK * NSP]      @ 8192   column-major: slot k of species s at [k*NSP+s]
//           1st-order terms are encoded as b = NSP (constant-1 pseudo-species).
#define WS_COUNTS 0
#define WS_TERMS  8192

__global__ __launch_bounds__(256) void scatter_kernel(
    const int* __restrict__ r1, const int* __restrict__ o1,
    const float* __restrict__ rates1, int n1,
    const int* __restrict__ r2a, const int* __restrict__ r2b,
    const int* __restrict__ o2, const float* __restrict__ rates2, int n2,
    const float* __restrict__ den_ptr,
    int* __restrict__ counts, int2* __restrict__ terms_T)
{
    const float den = den_ptr[0];
    const int total = n1 + n2;
    int i = blockIdx.x * blockDim.x + threadIdx.x;
    int stride = gridDim.x * blockDim.x;

    for (int t = i; t < total; t += stride) {
        int s, packed; float w;
        if (t < n1) {
            s = o1[t];
            packed = r1[t] | (NSP << 16);   // b = NSP -> ys[NSP] = 1.0 (1st-order)
            w = rates1[t];
        } else {
            int u = t - n1;
            s = o2[u];
            packed = r2a[u] | (r2b[u] << 16);
            w = rates2[u] * den;
        }
        int pos = atomicAdd(&counts[s], 1);
        if (pos < MAXK)
            terms_T[(size_t)pos * NSP + s] = make_int2(packed, __float_as_int(w));
    }
}

// grid = (batch/ROWS) * QUARTS blocks of 256 threads.
// blockIdx.x / QUARTS = row-group; blockIdx.x % QUARTS = species quarter.
// LDS = 2 * 1025 * 16 B ≈ 32.8 KB -> 2 blocks/CU co-resident (grid 512 on 256 CUs)
// = 8 waves/CU; unroll-4 ILP covers the terms_T L2 latency.
__global__ __launch_bounds__(BLK) void gather_kernel(
    const float* __restrict__ y,
    const int* __restrict__ counts,
    const int2* __restrict__ terms_T,
    float* __restrict__ out)
{
    // Eight batch rows interleaved as 2x float4 -> two ds_read_b128 per operand.
    // Entry NSP is the constant-1 pseudo-species for 1st-order terms.
    __shared__ float4 ysA[NSP + 1];   // rows 0..3
    __shared__ float4 ysB[NSP + 1];   // rows 4..7

    const int tid   = threadIdx.x;
    const int rg    = blockIdx.x / QUARTS;
    const int quart = blockIdx.x % QUARTS;
    const int row0  = rg * ROWS;

    // Stage all 8 rows (8192 floats) with 256 threads (coalesced global reads).
    for (int i = tid; i < ROWS * NSP; i += BLK) {
        int r = i >> 10;
        int c = i & (NSP - 1);
        float v = y[(size_t)(row0 + r) * NSP + c];
        float* dst = (r < 4) ? (float*)&ysA[c] : (float*)&ysB[c];
        dst[r & 3] = v;
    }
    if (tid == 0) {
        ysA[NSP] = make_float4(1.f, 1.f, 1.f, 1.f);
        ysB[NSP] = make_float4(1.f, 1.f, 1.f, 1.f);
    }
    __syncthreads();

    const int s   = quart * BLK + tid;   // this thread's species
    const int cnt = counts[s];           // merged term count, slots [0, cnt)

    float4 acc0 = make_float4(0.f, 0.f, 0.f, 0.f);
    float4 acc1 = make_float4(0.f, 0.f, 0.f, 0.f);

#pragma unroll 4
    for (int k = 0; k < cnt; ++k) {
        const int2 e = terms_T[(size_t)k * NSP + s];
        const int a = e.x & 0xFFFF;
        const int b = ((unsigned)e.x) >> 16;
        const float w = __int_as_float(e.y);
        const float4 a0 = ysA[a];
        const float4 a1 = ysB[a];
        const float4 b0 = ysA[b];
        const float4 b1 = ysB[b];
        acc0.x += w * a0.x * b0.x;
        acc0.y += w * a0.y * b0.y;
        acc0.z += w * a0.z * b0.z;
        acc0.w += w * a0.w * b0.w;
        acc1.x += w * a1.x * b1.x;
        acc1.y += w * a1.y * b1.y;
        acc1.z += w * a1.z * b1.z;
        acc1.w += w * a1.w * b1.w;
    }

    out[(size_t)(row0 + 0) * NSP + s] = acc0.x;
    out[(size_t)(row0 + 1) * NSP + s] = acc0.y;
    out[(size_t)(row0 + 2) * NSP + s] = acc0.z;
    out[(size_t)(row0 + 3) * NSP + s] = acc0.w;
    out[(size_t)(row0 + 4) * NSP + s] = acc1.x;
    out[(size_t)(row0 + 5) * NSP + s] = acc1.y;
    out[(size_t)(row0 + 6) * NSP + s] = acc1.z;
    out[(size_t)(row0 + 7) * NSP + s] = acc1.w;
}

extern "C" void kernel_launch(void* const* d_in, const int* in_sizes, int n_in,
                              void* d_out, int out_size, void* d_ws, size_t ws_size,
                              hipStream_t stream) {
    const float* y      = (const float*)d_in[1];
    const float* rates1 = (const float*)d_in[2];
    const float* rates2 = (const float*)d_in[3];
    const float* den    = (const float*)d_in[4];
    const int* r1  = (const int*)d_in[5];
    const int* r2a = (const int*)d_in[6];
    const int* r2b = (const int*)d_in[7];
    const int* o1  = (const int*)d_in[8];
    const int* o2  = (const int*)d_in[9];
    float* out = (float*)d_out;

    const int n_t1  = in_sizes[2];
    const int n_t2  = in_sizes[3];
    const int batch = in_sizes[1] / NSP;

    char* ws = (char*)d_ws;
    int*  counts  = (int*)(ws + WS_COUNTS);
    int2* terms_T = (int2*)(ws + WS_TERMS);

    hipMemsetAsync(counts, 0, NSP * sizeof(int), stream);

    int total   = n_t1 + n_t2;
    int sblocks = (total + 255) / 256;       // ~1 term per thread
    if (sblocks > 2048) sblocks = 2048;
    scatter_kernel<<<sblocks, 256, 0, stream>>>(r1, o1, rates1, n_t1,
                                                r2a, r2b, o2, rates2, n_t2,
                                                den, counts, terms_T);
    gather_kernel<<<(batch / ROWS) * QUARTS, BLK, 0, stream>>>(y, counts, terms_T, out);
}

// Round 2
// 116.459 us; speedup vs baseline: 1.0172x; 1.0172x over previous
//
#include <hip/hip_runtime.h>

#define NSP    1024
#define ROWS   4     // batch rows per row-group (proven best: 1024 blocks, 4/CU, 16 waves/CU)
#define BLK    256   // gather block: 256 threads, each owns 1 species of a quarter
#define QUARTS 4     // species quarters per row-group
#define MAXK   160   // max merged terms per species column (Poisson λ≈78; observed max ≈ 106)

// ---- workspace layout (bytes) ----
// counts  : int[NSP]                @ 0      (merged 1st+2nd order count per species)
// terms_P : int4[(MAXK/2) * NSP]    @ 8192   pair-major: pair p of species s at [p*NSP+s]
//           pair holds terms 2p (.x,.y) and 2p+1 (.z,.w); term = (a | b<<16, f32 weight)
//           1st-order terms encode b = NSP (constant-1 pseudo-species, broadcast read).
#define WS_COUNTS 0
#define WS_TERMS  8192

__global__ __launch_bounds__(256) void scatter_kernel(
    const int* __restrict__ r1, const int* __restrict__ o1,
    const float* __restrict__ rates1, int n1,
    const int* __restrict__ r2a, const int* __restrict__ r2b,
    const int* __restrict__ o2, const float* __restrict__ rates2, int n2,
    const float* __restrict__ den_ptr,
    int* __restrict__ counts, int2* __restrict__ terms_H)   // int2 view of terms_P
{
    const float den = den_ptr[0];
    const int total = n1 + n2;
    int t = blockIdx.x * blockDim.x + threadIdx.x;
    if (t >= total) return;

    int s, packed; float w;
    if (t < n1) {
        s = o1[t];
        packed = r1[t] | (NSP << 16);   // b = NSP -> ys[NSP] = 1.0 (1st-order)
        w = rates1[t];
    } else {
        int u = t - n1;
        s = o2[u];
        packed = r2a[u] | (r2b[u] << 16);
        w = rates2[u] * den;
    }
    int pos = atomicAdd(&counts[s], 1);
    if (pos < MAXK) {
        int p = pos >> 1, h = pos & 1;
        terms_H[((size_t)p * NSP + s) * 2 + h] = make_int2(packed, __float_as_int(w));
    }
}

// grid = (batch/ROWS) * QUARTS blocks of 256 threads.
// blockIdx.x / QUARTS = row-group; blockIdx.x % QUARTS = species quarter.
// LDS = 1025 * 16 B ≈ 16.4 KB -> 4 blocks/CU co-resident = 16 waves/CU.
__global__ __launch_bounds__(BLK) void gather_kernel(
    const float* __restrict__ y,
    const int* __restrict__ counts,
    const int4* __restrict__ terms_P,
    float* __restrict__ out)
{
    // Four batch rows interleaved as float4 -> one ds_read_b128 serves all 4 rows.
    // Entry NSP is the constant-1 pseudo-species for 1st-order terms (broadcast = conflict-free).
    __shared__ float4 ys[NSP + 1];

    const int tid   = threadIdx.x;
    const int rg    = blockIdx.x / QUARTS;
    const int quart = blockIdx.x % QUARTS;
    const int row0  = rg * ROWS;

    // Stage 4 rows (4096 floats) via float4 global loads (4 per thread, coalesced).
    const float4* y4 = (const float4*)(y + (size_t)row0 * NSP);
    for (int i = tid; i < ROWS * (NSP / 4); i += BLK) {
        int r  = i >> 8;          // NSP/4 = 256 float4 per row
        int c4 = i & 255;
        float4 v = y4[r * (NSP / 4) + c4];
        ((float*)&ys[4 * c4 + 0])[r] = v.x;
        ((float*)&ys[4 * c4 + 1])[r] = v.y;
        ((float*)&ys[4 * c4 + 2])[r] = v.z;
        ((float*)&ys[4 * c4 + 3])[r] = v.w;
    }
    if (tid == 0)
        ys[NSP] = make_float4(1.f, 1.f, 1.f, 1.f);
    __syncthreads();

    const int s   = quart * BLK + tid;   // this thread's species
    const int cnt = counts[s];           // merged term count, slots [0, cnt)

    float4 acc = make_float4(0.f, 0.f, 0.f, 0.f);

    const int np = cnt >> 1;             // full pairs
#pragma unroll 2
    for (int p = 0; p < np; ++p) {
        const int4 e = terms_P[(size_t)p * NSP + s];
        {
            const int a = e.x & 0xFFFF;
            const int b = ((unsigned)e.x) >> 16;
            const float w = __int_as_float(e.y);
            const float4 ya = ys[a];
            const float4 yb = ys[b];
            acc.x += w * ya.x * yb.x;
            acc.y += w * ya.y * yb.y;
            acc.z += w * ya.z * yb.z;
            acc.w += w * ya.w * yb.w;
        }
        {
            const int a = e.z & 0xFFFF;
            const int b = ((unsigned)e.z) >> 16;
            const float w = __int_as_float(e.w);
            const float4 ya = ys[a];
            const float4 yb = ys[b];
            acc.x += w * ya.x * yb.x;
            acc.y += w * ya.y * yb.y;
            acc.z += w * ya.z * yb.z;
            acc.w += w * ya.w * yb.w;
        }
    }
    if (cnt & 1) {   // odd tail: term index cnt-1 = 2*np, half 0
        const int2 e = ((const int2*)terms_P)[((size_t)np * NSP + s) * 2];
        const int a = e.x & 0xFFFF;
        const int b = ((unsigned)e.x) >> 16;
        const float w = __int_as_float(e.y);
        const float4 ya = ys[a];
        const float4 yb = ys[b];
        acc.x += w * ya.x * yb.x;
        acc.y += w * ya.y * yb.y;
        acc.z += w * ya.z * yb.z;
        acc.w += w * ya.w * yb.w;
    }

    out[(size_t)(row0 + 0) * NSP + s] = acc.x;
    out[(size_t)(row0 + 1) * NSP + s] = acc.y;
    out[(size_t)(row0 + 2) * NSP + s] = acc.z;
    out[(size_t)(row0 + 3) * NSP + s] = acc.w;
}

extern "C" void kernel_launch(void* const* d_in, const int* in_sizes, int n_in,
                              void* d_out, int out_size, void* d_ws, size_t ws_size,
                              hipStream_t stream) {
    const float* y      = (const float*)d_in[1];
    const float* rates1 = (const float*)d_in[2];
    const float* rates2 = (const float*)d_in[3];
    const float* den    = (const float*)d_in[4];
    const int* r1  = (const int*)d_in[5];
    const int* r2a = (const int*)d_in[6];
    const int* r2b = (const int*)d_in[7];
    const int* o1  = (const int*)d_in[8];
    const int* o2  = (const int*)d_in[9];
    float* out = (float*)d_out;

    const int n_t1  = in_sizes[2];
    const int n_t2  = in_sizes[3];
    const int batch = in_sizes[1] / NSP;

    char* ws = (char*)d_ws;
    int*  counts  = (int*)(ws + WS_COUNTS);
    int4* terms_P = (int4*)(ws + WS_TERMS);

    hipMemsetAsync(counts, 0, NSP * sizeof(int), stream);

    const int total   = n_t1 + n_t2;
    const int sblocks = (total + 255) / 256;   // 1 term per thread
    scatter_kernel<<<sblocks, 256, 0, stream>>>(r1, o1, rates1, n_t1,
                                                r2a, r2b, o2, rates2, n_t2,
                                                den, counts, (int2*)terms_P);
    gather_kernel<<<(batch / ROWS) * QUARTS, BLK, 0, stream>>>(y, counts, terms_P, out);
}